// Round 14
// baseline (138.086 us; speedup 1.0000x reference)
//
#include <hip/hip_runtime.h>

// ---------------------------------------------------------------------------
// Fully-fused KAN-conv MLP: ONE WAVE = ONE IMAGE, zero __syncthreads.
// Cardinal cubic B-spline: basis_j(x) = B3(u - j), u = 2.5x+5.5 (4 taps).
// Per-wave LDS slice: bas[pix] = uint4 (8 f16 taps) + slu16[pix] = silu f16.
// R14 = R12 chunk-outer structure (best: 66.4 us) +
//  - conv1 row loop NOT unrolled (code ~9KB -> ~2.5KB; tests I-fetch limit)
//  - slu in f16 (15.2 KB LDS -> 10 blocks/CU)
//  - fc1 double-buffered global W1p4 loads (vmcnt, in-order -> real prefetch)
// h3 / hpk / fc1out live in dead regions of bas after conv3 (post-read order
// safe: per-wave DS is in-order; all conv reads precede the writes).
// ---------------------------------------------------------------------------

typedef _Float16 h2 __attribute__((ext_vector_type(2)));

__device__ __forceinline__ h2 u2h(unsigned int u) {
  union { unsigned int x; h2 h; } v; v.x = u; return v.h;
}
__device__ __forceinline__ unsigned short f2h_bits(float x) {
  union { _Float16 h; unsigned short u; } v; v.h = (_Float16)x; return v.u;
}
__device__ __forceinline__ float h2f(unsigned short u) {
  union { unsigned short u; _Float16 h; } v; v.u = u; return (float)v.h;
}
__device__ __forceinline__ unsigned int pack2h(float a, float b) {
  return (unsigned int)f2h_bits(a) | ((unsigned int)f2h_bits(b) << 16);
}
__device__ __forceinline__ float fdot2(h2 a, h2 b, float c) {
  return __builtin_amdgcn_fdot2(a, b, c, false);
}

// Basis window (8 f16 packed in uint4) + silu, all in registers.
__device__ __forceinline__ void featurize_regs(float v, uint4& bs, float& silu) {
  silu = v / (1.0f + __expf(-v));
  bs.x = 0u; bs.y = 0u; bs.z = 0u; bs.w = 0u;
  float u = fmaf(v, 2.5f, 5.5f);
  if (u >= 0.0f && u < 11.0f) {
    float tf = floorf(u);
    float f = u - tf, f2 = f * f, f3 = f2 * f, om = 1.0f - f;
    const float c6 = 1.0f / 6.0f;
    float w0 = om * om * om * c6;
    float w1 = (3.0f * f3 - 6.0f * f2 + 4.0f) * c6;
    float w2 = (-3.0f * f3 + 3.0f * f2 + 3.0f * f + 1.0f) * c6;
    float w3 = f3 * c6;
    unsigned long long w01 =
        (unsigned long long)f2h_bits(w0) |
        ((unsigned long long)f2h_bits(w1) << 16) |
        ((unsigned long long)f2h_bits(w2) << 32) |
        ((unsigned long long)f2h_bits(w3) << 48);
    int t = (int)tf;                 // 0..10; window starts at slot t-3
    int s = 16 * t - 48;             // bit shift into 128-bit field
    unsigned long long lo, hi;
    if (s >= 0) {
      lo = (s < 64) ? (w01 << s) : 0ull;
      hi = (s == 0) ? 0ull : ((s < 64) ? (w01 >> (64 - s)) : (w01 << (s - 64)));
    } else {
      lo = w01 >> (-s);
      hi = 0ull;
    }
    bs.x = (unsigned int)lo; bs.y = (unsigned int)(lo >> 32);
    bs.z = (unsigned int)hi; bs.w = (unsigned int)(hi >> 32);
  }
}

// ---------------- prep: conv weights + W1p4 + padded W2 ---------------------
__global__ __launch_bounds__(256) void k_prep(
    const float* __restrict__ bw1, const float* __restrict__ sw1,
    const float* __restrict__ bw2, const float* __restrict__ sw2,
    const float* __restrict__ bw3, const float* __restrict__ sw3,
    const float* __restrict__ w1, const float* __restrict__ w2,
    unsigned int* __restrict__ V1s, float* __restrict__ V1b,
    unsigned int* __restrict__ V2s, float* __restrict__ V2b,
    unsigned int* __restrict__ V3s, float* __restrict__ V3b,
    unsigned int* __restrict__ W1p4, float* __restrict__ W2p) {
  int t = blockIdx.x * 256 + threadIdx.x;
  if (t < 180) {  // L1: 9 taps x 5 outs x 4 pairs
    int p = t & 3, o = (t >> 2) % 5, in = t / 20;
    V1s[t] = pack2h(sw1[(o * 9 + in) * 8 + 2 * p], sw1[(o * 9 + in) * 8 + 2 * p + 1]);
  }
  if (t < 45)  { int o = t % 5, in = t / 5; V1b[t] = bw1[o * 9 + in]; }
  if (t < 900) { // L2: 45 taps x 5 outs x 4 pairs
    int p = t & 3, o = (t >> 2) % 5, in = t / 20;
    V2s[t] = pack2h(sw2[(o * 45 + in) * 8 + 2 * p], sw2[(o * 45 + in) * 8 + 2 * p + 1]);
  }
  if (t < 225) { int o = t % 5, in = t / 5; V2b[t] = bw2[o * 45 + in]; }
  if (t < 360) { // L3: 45 taps x 2 outs x 4 pairs
    int p = t & 3, o = (t >> 2) & 1, in = t / 8;
    V3s[t] = pack2h(sw3[(o * 45 + in) * 8 + 2 * p], sw3[(o * 45 + in) * 8 + 2 * p + 1]);
  }
  if (t < 90)  { int o = t % 2, in = t / 2; V3b[t] = bw3[o * 45 + in]; }
  if (t < 43008) {  // W1p4[((g*512)+o)*4+j]: j-th k-pair of group g, out o
    int j = t & 3, o = (t >> 2) & 511, g = t >> 11;
    int kp = g * 4 + j;
    W1p4[t] = (o < 500 && kp < 81)
                  ? pack2h(w1[o * 162 + 2 * kp], w1[o * 162 + 2 * kp + 1])
                  : 0u;
  }
  if (t < 5120) {   // W2p[10][512] zero-padded
    int o = t >> 9, k = t & 511;
    W2p[t] = (k < 500) ? w2[o * 500 + k] : 0.0f;
  }
}

// ---------------- the fused per-image kernel (one wave per block) -----------
__global__ __launch_bounds__(64, 2) void k_fused(
    const float* __restrict__ x,
    const unsigned int* __restrict__ V1s, const float* __restrict__ V1b,
    const unsigned int* __restrict__ V2s, const float* __restrict__ V2b,
    const unsigned int* __restrict__ V3s, const float* __restrict__ V3b,
    const unsigned int* __restrict__ W1p4, const float* __restrict__ W2p,
    const float* __restrict__ b1, const float* __restrict__ b2,
    float* __restrict__ out) {
  __shared__ uint4 bas[845];               // 13,520 B
  __shared__ unsigned short slu16[848];    //  1,696 B  -> 15.2 KB total
  float*        basF = (float*)bas;        // dword view of bas
  float*        h3f  = basF + 2048;        // h3 (162 f), post-read region
  unsigned int* hpk  = (unsigned int*)basF + 2560;  // 84 uints (16B aligned)
  const int b = blockIdx.x;
  const int lane = threadIdx.x;            // 0..63, one wave

  // P1: featurize input image (784 px)
  #pragma unroll 1
  for (int l = lane; l < 784; l += 64) {
    uint4 bs; float sl;
    featurize_regs(x[b * 784 + l], bs, sl);
    bas[l] = bs; slu16[l] = f2h_bits(sl);
  }

  // P2: conv1 (1->5) + 2x2 maxpool; 169 outputs in 3 chunks, staged in regs.
  // Row loop NOT unrolled (code-size); ky guard is wave-uniform per (r,dy).
  float h1v[3][5];
  #pragma unroll 1
  for (int it = 0; it < 3; ++it) {
    int p = it * 64 + lane;
    if (p < 169) {
      int py = p / 13, px = p % 13;
      int r0 = py * 2, c0 = px * 2;
      float wacc[4][5];
      #pragma unroll
      for (int wi = 0; wi < 4; ++wi)
        #pragma unroll
        for (int o = 0; o < 5; ++o) wacc[wi][o] = 0.0f;
      #pragma unroll 1
      for (int r = 0; r < 4; ++r) {
        uint4 q[4]; float sl[4];
        #pragma unroll
        for (int c = 0; c < 4; ++c) {
          q[c]  = bas[(r0 + r) * 28 + c0 + c];
          sl[c] = h2f(slu16[(r0 + r) * 28 + c0 + c]);
        }
        #pragma unroll
        for (int dy = 0; dy < 2; ++dy) {
          int ky = r - dy;                      // runtime-uniform
          if (ky >= 0 && ky < 3) {
            #pragma unroll
            for (int c = 0; c < 4; ++c) {
              h2 a0 = u2h(q[c].x), a1 = u2h(q[c].y),
                 a2 = u2h(q[c].z), a3 = u2h(q[c].w);
              #pragma unroll
              for (int dx = 0; dx < 2; ++dx) {
                int kx = c - dx;                // compile-time
                if (kx >= 0 && kx < 3) {
                  const unsigned int* wp = V1s + (ky * 3 + kx) * 20;
                  const float* bp = V1b + (ky * 3 + kx) * 5;
                  #pragma unroll
                  for (int o = 0; o < 5; ++o) {
                    float acc = wacc[dy * 2 + dx][o];
                    acc = fdot2(a0, u2h(wp[o * 4 + 0]), acc);
                    acc = fdot2(a1, u2h(wp[o * 4 + 1]), acc);
                    acc = fdot2(a2, u2h(wp[o * 4 + 2]), acc);
                    acc = fdot2(a3, u2h(wp[o * 4 + 3]), acc);
                    wacc[dy * 2 + dx][o] = fmaf(sl[c], bp[o], acc);
                  }
                }
              }
            }
          }
        }
      }
      #pragma unroll
      for (int o = 0; o < 5; ++o)
        h1v[it][o] = fmaxf(fmaxf(wacc[0][o], wacc[1][o]),
                           fmaxf(wacc[2][o], wacc[3][o]));
    }
  }
  // write featurized h1 (after ALL conv1 reads; in-order DS keeps this safe)
  #pragma unroll 1
  for (int it = 0; it < 3; ++it) {
    int p = it * 64 + lane;
    if (p < 169) {
      #pragma unroll
      for (int o = 0; o < 5; ++o) {
        uint4 bs; float sl;
        featurize_regs(h1v[it][o], bs, sl);
        bas[o * 169 + p] = bs; slu16[o * 169 + p] = f2h_bits(sl);
      }
    }
  }

  // P4: conv2 (5->5); 121 outputs in 2 chunks, staged in regs (R12 shape)
  float h2v[2][5];
  #pragma unroll 1
  for (int it = 0; it < 2; ++it) {
    int pos = it * 64 + lane;
    if (pos < 121) {
      int y = pos / 11, xx = pos % 11;
      float acc2[5];
      #pragma unroll
      for (int o = 0; o < 5; ++o) acc2[o] = 0.0f;
      #pragma unroll 1
      for (int cky = 0; cky < 15; ++cky) {
        int c = cky / 3, ky = cky - c * 3;
        int base = c * 169 + (y + ky) * 13 + xx;
        uint4 q0 = bas[base], q1 = bas[base + 1], q2 = bas[base + 2];
        float s0 = h2f(slu16[base]), s1 = h2f(slu16[base + 1]),
              s2 = h2f(slu16[base + 2]);
        uint4 wq[15]; float wb[15];
        const uint4* wp4 = (const uint4*)(V2s + cky * 60);
        const float* bp  = V2b + cky * 15;
        #pragma unroll
        for (int i = 0; i < 15; ++i) { wq[i] = wp4[i]; wb[i] = bp[i]; }
        #pragma unroll
        for (int kx = 0; kx < 3; ++kx) {
          uint4 q = (kx == 0) ? q0 : ((kx == 1) ? q1 : q2);
          float sl = (kx == 0) ? s0 : ((kx == 1) ? s1 : s2);
          h2 a0 = u2h(q.x), a1 = u2h(q.y), a2 = u2h(q.z), a3 = u2h(q.w);
          #pragma unroll
          for (int o = 0; o < 5; ++o) {
            uint4 w = wq[kx * 5 + o];
            float a = acc2[o];
            a = fdot2(a0, u2h(w.x), a);
            a = fdot2(a1, u2h(w.y), a);
            a = fdot2(a2, u2h(w.z), a);
            a = fdot2(a3, u2h(w.w), a);
            acc2[o] = fmaf(sl, wb[kx * 5 + o], a);
          }
        }
      }
      #pragma unroll
      for (int o = 0; o < 5; ++o) h2v[it][o] = acc2[o];
    }
  }
  // write featurized h2
  #pragma unroll 1
  for (int it = 0; it < 2; ++it) {
    int pos = it * 64 + lane;
    if (pos < 121) {
      #pragma unroll
      for (int o = 0; o < 5; ++o) {
        uint4 bs; float sl;
        featurize_regs(h2v[it][o], bs, sl);
        bas[o * 121 + pos] = bs; slu16[o * 121 + pos] = f2h_bits(sl);
      }
    }
  }

  // P6: conv3 (5->2); 81 outputs in 2 chunks, staged in regs (R12 shape)
  float h3v[2][2];
  #pragma unroll 1
  for (int it = 0; it < 2; ++it) {
    int pos = it * 64 + lane;
    if (pos < 81) {
      int y = pos / 9, xx = pos % 9;
      float acc3[2] = {0.f, 0.f};
      #pragma unroll 1
      for (int cky = 0; cky < 15; ++cky) {
        int c = cky / 3, ky = cky - c * 3;
        int base = c * 121 + (y + ky) * 11 + xx;
        uint4 q0 = bas[base], q1 = bas[base + 1], q2 = bas[base + 2];
        float s0 = h2f(slu16[base]), s1 = h2f(slu16[base + 1]),
              s2 = h2f(slu16[base + 2]);
        uint4 wq[6]; float wb[6];
        const uint4* wp4 = (const uint4*)(V3s + cky * 24);
        const float* bp  = V3b + cky * 6;
        #pragma unroll
        for (int i = 0; i < 6; ++i) { wq[i] = wp4[i]; wb[i] = bp[i]; }
        #pragma unroll
        for (int kx = 0; kx < 3; ++kx) {
          uint4 q = (kx == 0) ? q0 : ((kx == 1) ? q1 : q2);
          float sl = (kx == 0) ? s0 : ((kx == 1) ? s1 : s2);
          h2 a0 = u2h(q.x), a1 = u2h(q.y), a2 = u2h(q.z), a3 = u2h(q.w);
          #pragma unroll
          for (int o = 0; o < 2; ++o) {
            uint4 w = wq[kx * 2 + o];
            float a = acc3[o];
            a = fdot2(a0, u2h(w.x), a);
            a = fdot2(a1, u2h(w.y), a);
            a = fdot2(a2, u2h(w.z), a);
            a = fdot2(a3, u2h(w.w), a);
            acc3[o] = fmaf(sl, wb[kx * 2 + o], a);
          }
        }
      }
      h3v[it][0] = acc3[0]; h3v[it][1] = acc3[1];
    }
  }
  // write h3 (f32) into h3f (bas region, post-read), then pack to f16 pairs
  #pragma unroll 1
  for (int it = 0; it < 2; ++it) {
    int pos = it * 64 + lane;
    if (pos < 81) { h3f[pos] = h3v[it][0]; h3f[81 + pos] = h3v[it][1]; }
  }
  hpk[lane] = pack2h(h3f[2 * lane], h3f[2 * lane + 1]);
  {
    int i1 = 64 + lane;
    if (i1 < 84)
      hpk[i1] = (i1 < 81) ? pack2h(h3f[2 * i1], h3f[2 * i1 + 1]) : 0u;
  }

  // P7: fc1 (162->500) + bias + ReLU; 8 outs/lane; double-buffered global
  // loads (vmcnt is in-order & separate from LDS lgkmcnt -> real prefetch).
  float fa[8];
  #pragma unroll
  for (int i = 0; i < 8; ++i) fa[i] = 0.0f;
  {
    const uint4* hp4 = (const uint4*)hpk;
    const uint4* wbase = (const uint4*)W1p4 + lane;
    uint4 wA[8], wB[8];
    #pragma unroll
    for (int i = 0; i < 8; ++i) wA[i] = wbase[i * 64];   // group 0
    #pragma unroll 1
    for (int g = 0; g < 21; g += 2) {
      if (g + 1 < 21) {
        const uint4* p = wbase + (g + 1) * 512;
        #pragma unroll
        for (int i = 0; i < 8; ++i) wB[i] = p[i * 64];
      }
      {
        uint4 hk = hp4[g];
        #pragma unroll
        for (int i = 0; i < 8; ++i) {
          float a = fa[i];
          a = fdot2(u2h(hk.x), u2h(wA[i].x), a);
          a = fdot2(u2h(hk.y), u2h(wA[i].y), a);
          a = fdot2(u2h(hk.z), u2h(wA[i].z), a);
          a = fdot2(u2h(hk.w), u2h(wA[i].w), a);
          fa[i] = a;
        }
      }
      if (g + 2 < 21) {
        const uint4* p = wbase + (g + 2) * 512;
        #pragma unroll
        for (int i = 0; i < 8; ++i) wA[i] = p[i * 64];
      }
      if (g + 1 < 21) {
        uint4 hk = hp4[g + 1];
        #pragma unroll
        for (int i = 0; i < 8; ++i) {
          float a = fa[i];
          a = fdot2(u2h(hk.x), u2h(wB[i].x), a);
          a = fdot2(u2h(hk.y), u2h(wB[i].y), a);
          a = fdot2(u2h(hk.z), u2h(wB[i].z), a);
          a = fdot2(u2h(hk.w), u2h(wB[i].w), a);
          fa[i] = a;
        }
      }
    }
  }
  #pragma unroll
  for (int i = 0; i < 8; ++i) {
    int o = lane + 64 * i;
    float bb = (o < 500) ? b1[o] : 0.0f;
    float v = fa[i] + bb;
    basF[o] = (v > 0.0f && o < 500) ? v : 0.0f;  // fc1out[512] in bas[0..127]
  }

  // P8: fc2 (500->10): lane covers k = 8*lane..8*lane+7, shfl reduction
  float hv0, hv1, hv2, hv3, hv4, hv5, hv6, hv7;
  {
    const float4* hf = (const float4*)&basF[lane * 8];
    float4 ha = hf[0], hb = hf[1];
    hv0 = ha.x; hv1 = ha.y; hv2 = ha.z; hv3 = ha.w;
    hv4 = hb.x; hv5 = hb.y; hv6 = hb.z; hv7 = hb.w;
  }
  float acc10[10];
  #pragma unroll
  for (int o = 0; o < 10; ++o) {
    const float4* wp = (const float4*)&W2p[o * 512 + lane * 8];
    float4 w0 = wp[0], w1v = wp[1];
    float s = hv0 * w0.x + hv1 * w0.y + hv2 * w0.z + hv3 * w0.w;
    s += hv4 * w1v.x + hv5 * w1v.y + hv6 * w1v.z + hv7 * w1v.w;
    acc10[o] = s;
  }
  #pragma unroll
  for (int off = 32; off > 0; off >>= 1) {
    #pragma unroll
    for (int o = 0; o < 10; ++o) acc10[o] += __shfl_down(acc10[o], off);
  }
  if (lane == 0) {
    #pragma unroll
    for (int o = 0; o < 10; ++o) out[b * 10 + o] = acc10[o] + b2[o];
  }
}

// ---------------------------------------------------------------------------
extern "C" void kernel_launch(void* const* d_in, const int* in_sizes, int n_in,
                              void* d_out, int out_size, void* d_ws, size_t ws_size,
                              hipStream_t stream) {
  (void)in_sizes; (void)n_in; (void)out_size; (void)ws_size;
  const float* x   = (const float*)d_in[0];
  const float* bw1 = (const float*)d_in[1];
  const float* sw1 = (const float*)d_in[2];
  const float* bw2 = (const float*)d_in[3];
  const float* sw2 = (const float*)d_in[4];
  const float* bw3 = (const float*)d_in[5];
  const float* sw3 = (const float*)d_in[6];
  const float* w1  = (const float*)d_in[7];
  const float* b1  = (const float*)d_in[8];
  const float* w2  = (const float*)d_in[9];
  const float* b2  = (const float*)d_in[10];
  float* out = (float*)d_out;

  char* ws = (char*)d_ws;
  unsigned int* V1s  = (unsigned int*)(ws);           // 180 u   (720 B)
  float*        V1b  = (float*)(ws + 768);            // 45 f    (180 B)
  unsigned int* V2s  = (unsigned int*)(ws + 1024);    // 900 u   (3,600 B)
  float*        V2b  = (float*)(ws + 4672);           // 225 f   (900 B)
  unsigned int* V3s  = (unsigned int*)(ws + 5632);    // 360 u   (1,440 B)
  float*        V3b  = (float*)(ws + 7168);           // 90 f    (360 B)
  float*        W2p  = (float*)(ws + 7680);           // 5,120 f (20,480 B)
  unsigned int* W1p4 = (unsigned int*)(ws + 28672);   // 43,008 u (172,032 B)

  k_prep<<<168, 256, 0, stream>>>(bw1, sw1, bw2, sw2, bw3, sw3, w1, w2,
                                  V1s, V1b, V2s, V2b, V3s, V3b, W1p4, W2p);
  k_fused<<<2048, 64, 0, stream>>>(x, V1s, V1b, V2s, V2b, V3s, V3b,
                                   W1p4, W2p, b1, b2, out);
}